// Round 10
// baseline (288.390 us; speedup 1.0000x reference)
//
#include <hip/hip_runtime.h>
#include <hip/hip_bf16.h>

// MDN: B=65536, COND=32, D=16, H=256, K=16
//  pi = softmax(z@Wpi+bpi); sigma = diag_embed(exp(z@Wsig+bsig));
//  mu = z@Wmu+bmu; z = tanh(x@W1+b1)
//
// Write-bound: 1.145 GB output => ~177 us floor at 6.5 TB/s.
// Ladder: R2/R3 fused LDS-bounce 248us (4.65 TB/s). R4 shaping -6%.
// R5-R7 split-expand 3.5-4.3 TB/s: loads+stores share vmcnt; waits that
// consume loads drain all younger stores. R8 shfl-redistribute: 279 (worse).
// R9 = R3 + software-pipelined B fragments: next chunk's B loads issue
// BEFORE this chunk's stores, so the pre-MFMA vmcnt wait no longer drains
// the store queue (loads are older than stores). 8 store-drains/block -> 0.

typedef __attribute__((ext_vector_type(8))) short short8;   // 8 bf16
typedef __attribute__((ext_vector_type(4))) float f32x4;

#define NB 65536
#define TB 64          // batch rows per block
#define HID 256
#define CIN 32

// ws layout (bf16): wpi_t [16][256] | wsig_t [256][256] | wmu_t [256][256]
#define WPI_OFF  0
#define WSIG_OFF (16*256)
#define WMU_OFF  (16*256 + 256*256)

__global__ __launch_bounds__(256) void cvt_weights(
    const float* __restrict__ Wpi, const float* __restrict__ Wsig,
    const float* __restrict__ Wmu, __hip_bfloat16* __restrict__ wsb)
{
    int r = blockIdx.x;      // 0..527 = output col -> transposed row
    int k = threadIdx.x;     // 0..255 = H index
    if (r < 16)
        wsb[WPI_OFF + r*256 + k] = __float2bfloat16(Wpi[k*16 + r]);
    else if (r < 272)
        wsb[WSIG_OFF + (r-16)*256 + k] = __float2bfloat16(Wsig[k*256 + (r-16)]);
    else
        wsb[WMU_OFF + (r-272)*256 + k] = __float2bfloat16(Wmu[k*256 + (r-272)]);
}

__global__ __launch_bounds__(256, 3) void mdn_main(
    const float* __restrict__ x, const float* __restrict__ W1,
    const float* __restrict__ b1, const float* __restrict__ bpi,
    const float* __restrict__ bsig, const float* __restrict__ bmu,
    const __hip_bfloat16* __restrict__ wsb,
    float* __restrict__ out)
{
    // LDS: zs 33792B + scratch 20480B = 54272B -> 3 blocks/CU
    __shared__ alignas(16) __hip_bfloat16 zs[TB][264];
    __shared__ alignas(16) float scratch[4][32][40];   // per-wave [32][32+pad]

    const int t  = threadIdx.x;
    const int b0 = blockIdx.x * TB;

    const int w    = t >> 6;       // wave 0..3
    const int lane = t & 63;
    const int wm   = w >> 1;       // wave row 0..1  (32 batch rows each)
    const int wn   = w & 1;        // wave col 0..1  (32 out cols each)
    const int lr   = lane & 15;
    const int lk   = lane >> 4;

    // ---- B-fragment software pipeline: issue chunk 0 loads ASAP ----
    short8 bf0[8], bf1[8];
    {
        const __hip_bfloat16* wbase = wsb + WSIG_OFF;   // chunk 0
        const short8* B0 = reinterpret_cast<const short8*>(wbase + (wn*32 +      lr)*256);
        const short8* B1 = reinterpret_cast<const short8*>(wbase + (wn*32 + 16 + lr)*256);
        #pragma unroll
        for (int kk = 0; kk < 8; kk++) {
            const int fi = kk*4 + lk;
            bf0[kk] = B0[fi];
            bf1[kk] = B1[fi];
        }
    }

    float* out_pi  = out;
    float* out_sig = out + (size_t)NB*16;
    float* out_mu  = out + (size_t)NB*16 + (size_t)NB*4096;

    // ---- load x tile [64][32] into scratch-as-xs (coalesced float4) ----
    float* xs = &scratch[0][0][0];   // 8KB, dead after z-phase
    {
        const float4* gx4 = reinterpret_cast<const float4*>(x + (size_t)b0*CIN);
        float4* xs4 = reinterpret_cast<float4*>(xs);
        xs4[t]       = gx4[t];
        xs4[t + 256] = gx4[t + 256];
    }

    // ---- preload W1 column t ----
    float w1c[CIN];
    #pragma unroll
    for (int c = 0; c < CIN; c++) w1c[c] = W1[c*HID + t];
    const float b1t = b1[t];
    __syncthreads();

    // ---- z = tanh(x @ W1 + b1), thread t owns hidden unit t ----
    for (int r = 0; r < TB; r += 4) {
        float a0 = b1t, a1 = b1t, a2 = b1t, a3 = b1t;
        const float4* x0 = reinterpret_cast<const float4*>(xs + (r+0)*CIN);
        const float4* x1 = reinterpret_cast<const float4*>(xs + (r+1)*CIN);
        const float4* x2 = reinterpret_cast<const float4*>(xs + (r+2)*CIN);
        const float4* x3 = reinterpret_cast<const float4*>(xs + (r+3)*CIN);
        #pragma unroll
        for (int c4 = 0; c4 < CIN/4; c4++) {
            float4 v0 = x0[c4], v1 = x1[c4], v2 = x2[c4], v3 = x3[c4];
            float w0 = w1c[c4*4+0], w1 = w1c[c4*4+1], w2 = w1c[c4*4+2], w3 = w1c[c4*4+3];
            a0 += v0.x*w0; a0 += v0.y*w1; a0 += v0.z*w2; a0 += v0.w*w3;
            a1 += v1.x*w0; a1 += v1.y*w1; a1 += v1.z*w2; a1 += v1.w*w3;
            a2 += v2.x*w0; a2 += v2.y*w1; a2 += v2.z*w2; a2 += v2.w*w3;
            a3 += v3.x*w0; a3 += v3.y*w1; a3 += v3.z*w2; a3 += v3.w*w3;
        }
        zs[r+0][t] = __float2bfloat16(1.0f - 2.0f/(__expf(2.0f*a0)+1.0f));
        zs[r+1][t] = __float2bfloat16(1.0f - 2.0f/(__expf(2.0f*a1)+1.0f));
        zs[r+2][t] = __float2bfloat16(1.0f - 2.0f/(__expf(2.0f*a2)+1.0f));
        zs[r+3][t] = __float2bfloat16(1.0f - 2.0f/(__expf(2.0f*a3)+1.0f));
    }
    __syncthreads();
    // ======== no block barriers below this line ========

    const short8* A0 = reinterpret_cast<const short8*>(&zs[wm*32 +      lr][0]);
    const short8* A1 = reinterpret_cast<const short8*>(&zs[wm*32 + 16 + lr][0]);
    float* scr = &scratch[w][0][0];          // wave-private [32][40]

    // sigma fill-phase lane roles
    const int cidx = lane >> 2;
    const int q    = lane & 3;
    const int epos = cidx - 4*q;
    // mu fill-phase lane roles
    const int mrr = lane >> 3;               // 0..7
    const int mcc = (lane & 7) * 4;

    f32x4* const sig4 = reinterpret_cast<f32x4*>(out_sig);
    f32x4* const mu4  = reinterpret_cast<f32x4*>(out_mu);

    short8 pB[8];                            // pi B fragments (loaded in chunk 7)

    for (int chunk = 0; chunk < 8; chunk++) {
        const bool is_sig = (chunk < 4);
        const int c0 = (chunk & 3) * 64;

        // ---- MFMA k-loop consumes the pipelined bf registers ----
        f32x4 acc[2][2] = {};
        #pragma unroll
        for (int kk = 0; kk < 8; kk++) {
            const int fi = kk*4 + lk;
            short8 af0 = A0[fi];
            short8 af1 = A1[fi];
            acc[0][0] = __builtin_amdgcn_mfma_f32_16x16x32_bf16(af0, bf0[kk], acc[0][0], 0,0,0);
            acc[0][1] = __builtin_amdgcn_mfma_f32_16x16x32_bf16(af0, bf1[kk], acc[0][1], 0,0,0);
            acc[1][0] = __builtin_amdgcn_mfma_f32_16x16x32_bf16(af1, bf0[kk], acc[1][0], 0,0,0);
            acc[1][1] = __builtin_amdgcn_mfma_f32_16x16x32_bf16(af1, bf1[kk], acc[1][1], 0,0,0);
        }

        // ---- issue NEXT chunk's B loads now, BEFORE any stores, so the
        // pre-MFMA wait of chunk+1 never has to drain the store queue ----
        if (chunk < 7) {
            const int nc = chunk + 1;
            const __hip_bfloat16* nbase =
                wsb + (nc < 4 ? WSIG_OFF : WMU_OFF) + (size_t)((nc & 3)*64)*256;
            const short8* nB0 = reinterpret_cast<const short8*>(nbase + (wn*32 +      lr)*256);
            const short8* nB1 = reinterpret_cast<const short8*>(nbase + (wn*32 + 16 + lr)*256);
            #pragma unroll
            for (int kk = 0; kk < 8; kk++) {
                const int fi = kk*4 + lk;
                bf0[kk] = nB0[fi];
                bf1[kk] = nB1[fi];
            }
        } else {
            const short8* Bp = reinterpret_cast<const short8*>(wsb + WPI_OFF + lr*256);
            #pragma unroll
            for (int kk = 0; kk < 8; kk++) pB[kk] = Bp[kk*4 + lk];
        }

        // WAR: previous chunk's scr reads must be done
        asm volatile("s_waitcnt lgkmcnt(0)" ::: "memory");

        // ---- stage this wave's 32x32 value tile into private scratch ----
        #pragma unroll
        for (int ni = 0; ni < 2; ni++) {
            const int c = c0 + wn*32 + ni*16 + lr;
            const float bias = is_sig ? bsig[c] : bmu[c];
            #pragma unroll
            for (int mi = 0; mi < 2; mi++) {
                #pragma unroll
                for (int j = 0; j < 4; j++) {
                    const int row = mi*16 + lk*4 + j;
                    const int col = ni*16 + lr;
                    float v = acc[mi][ni][j] + bias;
                    scr[row*40 + col] = is_sig ? __expf(v) : v;
                }
            }
        }
        asm volatile("s_waitcnt lgkmcnt(0)" ::: "memory");

        // ---- coalesced fill phase (wave-local, no barrier) ----
        if (is_sig) {
            #pragma unroll 4
            for (int r = 0; r < 32; r++) {
                size_t base = (size_t)(b0 + wm*32 + r) * 1024
                            + (size_t)(c0 + wn*32) * 4 + lane;
                #pragma unroll
                for (int cb = 0; cb < 2; cb++) {
                    float val = scr[r*40 + cb*16 + cidx];
                    f32x4 v;
                    v[0] = (epos == 0) ? val : 0.0f;
                    v[1] = (epos == 1) ? val : 0.0f;
                    v[2] = (epos == 2) ? val : 0.0f;
                    v[3] = (epos == 3) ? val : 0.0f;
                    sig4[base + cb*64] = v;
                }
            }
        } else {
            #pragma unroll
            for (int it = 0; it < 4; it++) {
                const int r = it*8 + mrr;
                f32x4 v = *reinterpret_cast<const f32x4*>(&scr[r*40 + mcc]);
                size_t base = (size_t)(b0 + wm*32 + r) * 64
                            + (size_t)(c0 + wn*32) / 4 + (lane & 7);
                mu4[base] = v;
            }
        }
    }

    // ---- pi: 16 cols, each wave owns a 16-row m-tile; B pipelined above ----
    {
        const short8* Ap = reinterpret_cast<const short8*>(&zs[w*16 + lr][0]);
        f32x4 pacc = {};
        #pragma unroll
        for (int kk = 0; kk < 8; kk++) {
            short8 af = Ap[kk*4 + lk];
            pacc = __builtin_amdgcn_mfma_f32_16x16x32_bf16(af, pB[kk], pacc, 0,0,0);
        }
        const float bp = bpi[lr];
        #pragma unroll
        for (int j = 0; j < 4; j++) {
            float v = pacc[j] + bp;
            float m = v;
            m = fmaxf(m, __shfl_xor(m, 1));
            m = fmaxf(m, __shfl_xor(m, 2));
            m = fmaxf(m, __shfl_xor(m, 4));
            m = fmaxf(m, __shfl_xor(m, 8));
            float e = __expf(v - m);
            float s = e;
            s += __shfl_xor(s, 1);
            s += __shfl_xor(s, 2);
            s += __shfl_xor(s, 4);
            s += __shfl_xor(s, 8);
            const int b = b0 + w*16 + lk*4 + j;
            out_pi[(size_t)b*16 + lr] = e / s;
        }
    }
}

extern "C" void kernel_launch(void* const* d_in, const int* in_sizes, int n_in,
                              void* d_out, int out_size, void* d_ws, size_t ws_size,
                              hipStream_t stream) {
    (void)in_sizes; (void)n_in; (void)out_size; (void)ws_size;
    const float* x    = (const float*)d_in[0];
    const float* W1   = (const float*)d_in[1];
    const float* b1   = (const float*)d_in[2];
    const float* Wpi  = (const float*)d_in[3];
    const float* bpi  = (const float*)d_in[4];
    const float* Wsig = (const float*)d_in[5];
    const float* bsig = (const float*)d_in[6];
    const float* Wmu  = (const float*)d_in[7];
    const float* bmu  = (const float*)d_in[8];
    float* out = (float*)d_out;
    __hip_bfloat16* wsb = (__hip_bfloat16*)d_ws;   // 270336 bytes used

    cvt_weights<<<528, 256, 0, stream>>>(Wpi, Wsig, Wmu, wsb);
    mdn_main<<<NB/TB, 256, 0, stream>>>(x, W1, b1, bpi, bsig, bmu, wsb, out);
}

// Round 11
// 270.939 us; speedup vs baseline: 1.0644x; 1.0644x over previous
//
#include <hip/hip_runtime.h>
#include <hip/hip_bf16.h>

// MDN: B=65536, COND=32, D=16, H=256, K=16
//  pi = softmax(z@Wpi+bpi); sigma = diag_embed(exp(z@Wsig+bsig));
//  mu = z@Wmu+bmu; z = tanh(x@W1+b1)
//
// Write-bound: 1.145 GB output => ~177 us floor at 6.5 TB/s.
// Ladder: R3 fused LDS-bounce 248us (4.65 TB/s effective) beats all 8
// alternative structures (nt, burst shaping, splits, sweeps, shfl, B-pipe).
// R10: transplant fillBuffer's STREAM TOPOLOGY into R3: grid=256 (1 block/CU),
// each block serially processes 4 consecutive 64-row tiles -> 32 contiguous
// write streams per XCD (vs 96-256 before), so the 4MB per-XCD L2 can
// assemble full pages before writeback. fillBuffer runs at 11% occupancy;
// store-bound work doesn't need waves, it needs few fat streams.

typedef __attribute__((ext_vector_type(8))) short short8;   // 8 bf16
typedef __attribute__((ext_vector_type(4))) float f32x4;

#define NB 65536
#define TB 64          // batch rows per tile
#define HID 256
#define CIN 32
#define TILES_PER_BLOCK 4

// ws layout (bf16): wpi_t [16][256] | wsig_t [256][256] | wmu_t [256][256]
#define WPI_OFF  0
#define WSIG_OFF (16*256)
#define WMU_OFF  (16*256 + 256*256)

__global__ __launch_bounds__(256) void cvt_weights(
    const float* __restrict__ Wpi, const float* __restrict__ Wsig,
    const float* __restrict__ Wmu, __hip_bfloat16* __restrict__ wsb)
{
    int r = blockIdx.x;      // 0..527 = output col -> transposed row
    int k = threadIdx.x;     // 0..255 = H index
    if (r < 16)
        wsb[WPI_OFF + r*256 + k] = __float2bfloat16(Wpi[k*16 + r]);
    else if (r < 272)
        wsb[WSIG_OFF + (r-16)*256 + k] = __float2bfloat16(Wsig[k*256 + (r-16)]);
    else
        wsb[WMU_OFF + (r-272)*256 + k] = __float2bfloat16(Wmu[k*256 + (r-272)]);
}

__global__ __launch_bounds__(256, 2) void mdn_main(
    const float* __restrict__ x, const float* __restrict__ W1,
    const float* __restrict__ b1, const float* __restrict__ bpi,
    const float* __restrict__ bsig, const float* __restrict__ bmu,
    const __hip_bfloat16* __restrict__ wsb,
    float* __restrict__ out)
{
    // LDS: zs 33792B + scratch 20480B + xs 8192B = 62464B (1 block/CU at grid 256)
    __shared__ alignas(16) __hip_bfloat16 zs[TB][264];
    __shared__ alignas(16) float scratch[4][32][40];   // per-wave [32][32+pad]
    __shared__ alignas(16) float xs[TB][CIN];

    const int t = threadIdx.x;

    float* out_pi  = out;
    float* out_sig = out + (size_t)NB*16;
    float* out_mu  = out + (size_t)NB*16 + (size_t)NB*4096;

    const int w    = t >> 6;       // wave 0..3
    const int lane = t & 63;
    const int wm   = w >> 1;       // wave row 0..1  (32 batch rows each)
    const int wn   = w & 1;        // wave col 0..1  (32 out cols each)
    const int lr   = lane & 15;
    const int lk   = lane >> 4;

    // ---- preload W1 column t (tile-invariant) ----
    float w1c[CIN];
    #pragma unroll
    for (int c = 0; c < CIN; c++) w1c[c] = W1[c*HID + t];
    const float b1t = b1[t];

    const short8* A0 = reinterpret_cast<const short8*>(&zs[wm*32 +      lr][0]);
    const short8* A1 = reinterpret_cast<const short8*>(&zs[wm*32 + 16 + lr][0]);
    float* scr = &scratch[w][0][0];          // wave-private [32][40]

    // sigma fill-phase lane roles
    const int cidx = lane >> 2;
    const int q    = lane & 3;
    const int epos = cidx - 4*q;
    // mu fill-phase lane roles
    const int mrr = lane >> 3;               // 0..7
    const int mcc = (lane & 7) * 4;

    f32x4* const sig4 = reinterpret_cast<f32x4*>(out_sig);
    f32x4* const mu4  = reinterpret_cast<f32x4*>(out_mu);

    for (int tile = 0; tile < TILES_PER_BLOCK; tile++) {
        const int b0 = (blockIdx.x * TILES_PER_BLOCK + tile) * TB;

        // WAR on zs/xs vs previous tile's readers
        __syncthreads();

        // ---- load x tile [64][32] (coalesced float4) ----
        {
            const float4* gx4 = reinterpret_cast<const float4*>(x + (size_t)b0*CIN);
            float4* xs4 = reinterpret_cast<float4*>(&xs[0][0]);
            xs4[t]       = gx4[t];
            xs4[t + 256] = gx4[t + 256];
        }
        __syncthreads();

        // ---- z = tanh(x @ W1 + b1), thread t owns hidden unit t ----
        for (int r = 0; r < TB; r += 4) {
            float a0 = b1t, a1 = b1t, a2 = b1t, a3 = b1t;
            const float4* x0 = reinterpret_cast<const float4*>(&xs[r+0][0]);
            const float4* x1 = reinterpret_cast<const float4*>(&xs[r+1][0]);
            const float4* x2 = reinterpret_cast<const float4*>(&xs[r+2][0]);
            const float4* x3 = reinterpret_cast<const float4*>(&xs[r+3][0]);
            #pragma unroll
            for (int c4 = 0; c4 < CIN/4; c4++) {
                float4 v0 = x0[c4], v1 = x1[c4], v2 = x2[c4], v3 = x3[c4];
                float w0 = w1c[c4*4+0], w1 = w1c[c4*4+1], w2 = w1c[c4*4+2], w3 = w1c[c4*4+3];
                a0 += v0.x*w0; a0 += v0.y*w1; a0 += v0.z*w2; a0 += v0.w*w3;
                a1 += v1.x*w0; a1 += v1.y*w1; a1 += v1.z*w2; a1 += v1.w*w3;
                a2 += v2.x*w0; a2 += v2.y*w1; a2 += v2.z*w2; a2 += v2.w*w3;
                a3 += v3.x*w0; a3 += v3.y*w1; a3 += v3.z*w2; a3 += v3.w*w3;
            }
            zs[r+0][t] = __float2bfloat16(1.0f - 2.0f/(__expf(2.0f*a0)+1.0f));
            zs[r+1][t] = __float2bfloat16(1.0f - 2.0f/(__expf(2.0f*a1)+1.0f));
            zs[r+2][t] = __float2bfloat16(1.0f - 2.0f/(__expf(2.0f*a2)+1.0f));
            zs[r+3][t] = __float2bfloat16(1.0f - 2.0f/(__expf(2.0f*a3)+1.0f));
        }
        __syncthreads();
        // ---- no barriers within the chunk/store phase ----

        for (int chunk = 0; chunk < 8; chunk++) {
            const bool is_sig = (chunk < 4);
            const int c0 = (chunk & 3) * 64;
            const __hip_bfloat16* wbase =
                wsb + (is_sig ? WSIG_OFF : WMU_OFF) + (size_t)c0*256;
            const short8* B0 = reinterpret_cast<const short8*>(wbase + (wn*32 +      lr)*256);
            const short8* B1 = reinterpret_cast<const short8*>(wbase + (wn*32 + 16 + lr)*256);

            f32x4 acc[2][2] = {};
            #pragma unroll
            for (int kk = 0; kk < 8; kk++) {
                const int fi = kk*4 + lk;
                short8 af0 = A0[fi];
                short8 af1 = A1[fi];
                short8 bf0 = B0[fi];
                short8 bf1 = B1[fi];
                acc[0][0] = __builtin_amdgcn_mfma_f32_16x16x32_bf16(af0, bf0, acc[0][0], 0,0,0);
                acc[0][1] = __builtin_amdgcn_mfma_f32_16x16x32_bf16(af0, bf1, acc[0][1], 0,0,0);
                acc[1][0] = __builtin_amdgcn_mfma_f32_16x16x32_bf16(af1, bf0, acc[1][0], 0,0,0);
                acc[1][1] = __builtin_amdgcn_mfma_f32_16x16x32_bf16(af1, bf1, acc[1][1], 0,0,0);
            }

            // WAR: previous chunk's scr reads must be done (wave-local)
            asm volatile("s_waitcnt lgkmcnt(0)" ::: "memory");

            // ---- stage this wave's 32x32 value tile into private scratch ----
            #pragma unroll
            for (int ni = 0; ni < 2; ni++) {
                const int c = c0 + wn*32 + ni*16 + lr;
                const float bias = is_sig ? bsig[c] : bmu[c];
                #pragma unroll
                for (int mi = 0; mi < 2; mi++) {
                    #pragma unroll
                    for (int j = 0; j < 4; j++) {
                        const int row = mi*16 + lk*4 + j;
                        const int col = ni*16 + lr;
                        float v = acc[mi][ni][j] + bias;
                        scr[row*40 + col] = is_sig ? __expf(v) : v;
                    }
                }
            }
            asm volatile("s_waitcnt lgkmcnt(0)" ::: "memory");

            // ---- coalesced fill phase (wave-local, no barrier) ----
            if (is_sig) {
                #pragma unroll 4
                for (int r = 0; r < 32; r++) {
                    size_t base = (size_t)(b0 + wm*32 + r) * 1024
                                + (size_t)(c0 + wn*32) * 4 + lane;
                    #pragma unroll
                    for (int cb = 0; cb < 2; cb++) {
                        float val = scr[r*40 + cb*16 + cidx];
                        f32x4 v;
                        v[0] = (epos == 0) ? val : 0.0f;
                        v[1] = (epos == 1) ? val : 0.0f;
                        v[2] = (epos == 2) ? val : 0.0f;
                        v[3] = (epos == 3) ? val : 0.0f;
                        sig4[base + cb*64] = v;
                    }
                }
            } else {
                #pragma unroll
                for (int it = 0; it < 4; it++) {
                    const int r = it*8 + mrr;
                    f32x4 v = *reinterpret_cast<const f32x4*>(&scr[r*40 + mcc]);
                    size_t base = (size_t)(b0 + wm*32 + r) * 64
                                + (size_t)(c0 + wn*32) / 4 + (lane & 7);
                    mu4[base] = v;
                }
            }
        }

        // ---- pi: 16 cols, each wave owns a 16-row m-tile ----
        {
            const short8* Ap = reinterpret_cast<const short8*>(&zs[w*16 + lr][0]);
            const short8* Bp = reinterpret_cast<const short8*>(wsb + WPI_OFF + lr*256);

            f32x4 pacc = {};
            #pragma unroll
            for (int kk = 0; kk < 8; kk++) {
                short8 af = Ap[kk*4 + lk];
                short8 bf = Bp[kk*4 + lk];
                pacc = __builtin_amdgcn_mfma_f32_16x16x32_bf16(af, bf, pacc, 0,0,0);
            }
            const float bp = bpi[lr];
            #pragma unroll
            for (int j = 0; j < 4; j++) {
                float v = pacc[j] + bp;
                float m = v;
                m = fmaxf(m, __shfl_xor(m, 1));
                m = fmaxf(m, __shfl_xor(m, 2));
                m = fmaxf(m, __shfl_xor(m, 4));
                m = fmaxf(m, __shfl_xor(m, 8));
                float e = __expf(v - m);
                float s = e;
                s += __shfl_xor(s, 1);
                s += __shfl_xor(s, 2);
                s += __shfl_xor(s, 4);
                s += __shfl_xor(s, 8);
                const int b = b0 + w*16 + lk*4 + j;
                out_pi[(size_t)b*16 + lr] = e / s;
            }
        }
    }
}

extern "C" void kernel_launch(void* const* d_in, const int* in_sizes, int n_in,
                              void* d_out, int out_size, void* d_ws, size_t ws_size,
                              hipStream_t stream) {
    (void)in_sizes; (void)n_in; (void)out_size; (void)ws_size;
    const float* x    = (const float*)d_in[0];
    const float* W1   = (const float*)d_in[1];
    const float* b1   = (const float*)d_in[2];
    const float* Wpi  = (const float*)d_in[3];
    const float* bpi  = (const float*)d_in[4];
    const float* Wsig = (const float*)d_in[5];
    const float* bsig = (const float*)d_in[6];
    const float* Wmu  = (const float*)d_in[7];
    const float* bmu  = (const float*)d_in[8];
    float* out = (float*)d_out;
    __hip_bfloat16* wsb = (__hip_bfloat16*)d_ws;   // 270336 bytes used

    cvt_weights<<<528, 256, 0, stream>>>(Wpi, Wsig, Wmu, wsb);
    mdn_main<<<NB/(TB*TILES_PER_BLOCK), 256, 0, stream>>>(
        x, W1, b1, bpi, bsig, bmu, wsb, out);
}